// Round 3
// baseline (797.366 us; speedup 1.0000x reference)
//
#include <hip/hip_runtime.h>

#define Hh 512
#define Pp 256
#define Ll 4096
#define Bb 8
#define BL (Bb*Ll)      // 32768
#define Sc 64           // chunk size
#define NC 64           // chunks per sequence

// ws offsets in float2 units
#define LAM_OFF   0                       // f32 lambda_bar [256]
#define G_OFF     256                     // f32 g [256]
#define LAMS64D_OFF 512                   // double2 lambda_bar^64 [256] = 512 float2 slots
#define BBART_OFF 1024                    // [h*256+p], 131072 float2
#define CT_OFF    (BBART_OFF + 131072)    // [p*512+h], 131072 float2
#define BU_OFF    (CT_OFF + 131072)       // [ (b*L+l)*256 + p ], 8388608 float2
#define AGG_OFF   (BU_OFF + 8388608)      // [ (b*NC+c)*256 + p ], 131072 float2
#define CARRY_OFF (AGG_OFF + 131072)      // same shape

#define OUT_ELEMS 16777216                // B*L*H floats; then state: planar [2048 re][2048 im]

// ---- K0a: per-p scalars in DOUBLE: lambda_bar, lambda_bar^64 (kept f64), g ----
__global__ void k0a(const float* __restrict__ Lre, const float* __restrict__ Lim,
                    const float* __restrict__ logstep, float2* __restrict__ ws) {
    int p = threadIdx.x;
    double lr = (double)Lre[p], li = (double)Lim[p];
    double st = exp((double)logstep[p]);
    double a  = lr * st;          // real part of Lambda*step
    double th = li * st;          // imag part
    double er = exp(a);
    double lamr = er * cos(th), lami = er * sin(th);
    ws[LAM_OFF + p] = make_float2((float)lamr, (float)lami);
    double er64 = exp(64.0 * a);
    double th64 = 64.0 * th;
    double2* lam64 = (double2*)(ws + LAMS64D_OFF);
    lam64[p] = make_double2(er64 * cos(th64), er64 * sin(th64));
    // g = (lam - 1) / Lambda  (complex divide, double)
    double nr = lamr - 1.0, ni = lami;
    double den = lr*lr + li*li;
    double gr = (nr*lr + ni*li) / den;
    double gi = (ni*lr - nr*li) / den;
    ws[G_OFF + p] = make_float2((float)gr, (float)gi);
}

// ---- K0b: Bbar_t[h*256+p] = g[p] * (B[p][h][0] + i B[p][h][1]) ----
__global__ void k0b(const float* __restrict__ Bmat, float2* __restrict__ ws) {
    int idx = blockIdx.x * 256 + threadIdx.x;   // 0..131071, = p*512+h
    int p = idx >> 9, h = idx & 511;
    float2 b = ((const float2*)Bmat)[idx];
    float2 g = ws[G_OFF + p];
    float2 o;
    o.x = g.x*b.x - g.y*b.y;
    o.y = g.x*b.y + g.y*b.x;
    ws[BBART_OFF + h*Pp + p] = o;
}

// ---- K0c: Ct[p*512+h] = C[h][p] (complex) ----
__global__ void k0c(const float* __restrict__ Cmat, float2* __restrict__ ws) {
    int idx = blockIdx.x * 256 + threadIdx.x;   // = h*256+p
    int h = idx >> 8, p = idx & 255;
    float2 c = ((const float2*)Cmat)[idx];
    ws[CT_OFF + p*Hh + h] = c;
}

// ---- K1: Bu[(r)*256+p] = sum_h u[r][h] * Bbar_t[h][p]  (r = b*L+l) ----
__global__ void k1(const float* __restrict__ u, float2* __restrict__ ws) {
    __shared__ float su[8 * Hh];     // 16 KB
    int p = threadIdx.x;
    long r0 = (long)blockIdx.x * 8;
    const float* usrc = u + r0 * Hh;
    for (int i = p; i < 8 * Hh; i += 256) su[i] = usrc[i];
    __syncthreads();
    const float2* __restrict__ bb = ws + BBART_OFF;
    float accr[8] = {0,0,0,0,0,0,0,0};
    float acci[8] = {0,0,0,0,0,0,0,0};
    for (int h = 0; h < Hh; ++h) {
        float2 w = bb[h * Pp + p];
        #pragma unroll
        for (int m = 0; m < 8; ++m) {
            float us = su[m * Hh + h];
            accr[m] = fmaf(us, w.x, accr[m]);
            acci[m] = fmaf(us, w.y, acci[m]);
        }
    }
    float2* __restrict__ Bu = ws + BU_OFF;
    #pragma unroll
    for (int m = 0; m < 8; ++m)
        Bu[(r0 + m) * Pp + p] = make_float2(accr[m], acci[m]);
}

// ---- K2a: per-chunk aggregate (chunk-local scan end value) ----
__global__ void k2a(float2* __restrict__ ws) {
    int p = threadIdx.x;
    int bc = blockIdx.x;              // 0..511 = b*NC + c
    int b = bc >> 6, c = bc & 63;
    float2 lam = ws[LAM_OFF + p];
    const float2* __restrict__ Bu = ws + BU_OFF + ((long)(b*Ll + c*Sc)) * Pp + p;
    float2 agg = make_float2(0.f, 0.f);
    for (int j = 0; j < Sc; ++j) {
        float2 bu = Bu[(long)j * Pp];
        float nr = fmaf(lam.x, agg.x, bu.x); nr = fmaf(-lam.y, agg.y, nr);
        float ni = fmaf(lam.x, agg.y, bu.y); ni = fmaf( lam.y, agg.x, ni);
        agg.x = nr; agg.y = ni;
    }
    ws[AGG_OFF + bc * Pp + p] = agg;
}

// ---- K2b: sequential scan over chunk aggregates -> carry-in per chunk (DOUBLE chain) ----
__global__ void k2b(float2* __restrict__ ws) {   // 8 blocks x 256
    int p = threadIdx.x, b = blockIdx.x;
    const double2* lam64 = (const double2*)(ws + LAMS64D_OFF);
    double2 lS = lam64[p];
    double cr = 0.0, ci = 0.0;
    for (int c = 0; c < NC; ++c) {
        ws[CARRY_OFF + (b*NC + c) * Pp + p] = make_float2((float)cr, (float)ci);
        float2 a = ws[AGG_OFF + (b*NC + c) * Pp + p];
        double nr = fma(lS.x, cr, (double)a.x); nr = fma(-lS.y, ci, nr);
        double ni = fma(lS.x, ci, (double)a.y); ni = fma( lS.y, cr, ni);
        cr = nr; ci = ni;
    }
}

// ---- K2c: apply carry-in, rewrite Bu -> xs in place; emit final state (PLANAR re/im) ----
__global__ void k2c(float2* __restrict__ ws, float* __restrict__ dout) {
    int p = threadIdx.x;
    int bc = blockIdx.x;
    int b = bc >> 6, c = bc & 63;
    float2 lam = ws[LAM_OFF + p];
    float2 x = ws[CARRY_OFF + bc * Pp + p];
    float2* __restrict__ Bu = ws + BU_OFF + ((long)(b*Ll + c*Sc)) * Pp + p;
    for (int j = 0; j < Sc; ++j) {
        float2 bu = Bu[(long)j * Pp];
        float nr = fmaf(lam.x, x.x, bu.x); nr = fmaf(-lam.y, x.y, nr);
        float ni = fmaf(lam.x, x.y, bu.y); ni = fmaf( lam.y, x.x, ni);
        x.x = nr; x.y = ni;
        Bu[(long)j * Pp] = x;
    }
    if (c == NC - 1) {
        // planar complex layout: [B*P reals][B*P imags]
        dout[OUT_ELEMS + b * Pp + p] = x.x;
        dout[OUT_ELEMS + Bb * Pp + b * Pp + p] = x.y;
    }
}

// ---- K3: out[r][h] = 2*Re(sum_p xs[r][p]*Ct[p][h]) + D[h]*u[r][h] ----
__global__ void k3(const float* __restrict__ u, const float* __restrict__ Dv,
                   const float2* __restrict__ ws, float* __restrict__ out) {
    __shared__ float2 sx[8 * Pp];    // 16 KB
    int t = threadIdx.x;             // 0..511
    long r0 = (long)blockIdx.x * 8;
    const float2* __restrict__ xs = ws + BU_OFF + r0 * Pp;
    for (int i = t; i < 8 * Pp; i += 512) sx[i] = xs[i];
    __syncthreads();
    int h = t;
    const float2* __restrict__ Ct = ws + CT_OFF + h;
    float acc[8] = {0,0,0,0,0,0,0,0};
    for (int pp = 0; pp < Pp; ++pp) {
        float2 c = Ct[(long)pp * Hh];
        #pragma unroll
        for (int m = 0; m < 8; ++m) {
            float2 x = sx[m * Pp + pp];
            acc[m] = fmaf(x.x, c.x, acc[m]);
            acc[m] = fmaf(-x.y, c.y, acc[m]);
        }
    }
    float d = Dv[h];
    #pragma unroll
    for (int m = 0; m < 8; ++m) {
        long o = (r0 + m) * Hh + h;
        out[o] = 2.f * acc[m] + d * u[o];
    }
}

extern "C" void kernel_launch(void* const* d_in, const int* in_sizes, int n_in,
                              void* d_out, int out_size, void* d_ws, size_t ws_size,
                              hipStream_t stream) {
    const float* u       = (const float*)d_in[0];
    const float* Lre     = (const float*)d_in[1];
    const float* Lim     = (const float*)d_in[2];
    const float* Bmat    = (const float*)d_in[3];
    const float* Cmat    = (const float*)d_in[4];
    const float* Dv      = (const float*)d_in[5];
    const float* logstep = (const float*)d_in[6];
    float*  out = (float*)d_out;
    float2* ws  = (float2*)d_ws;

    k0a<<<1, 256, 0, stream>>>(Lre, Lim, logstep, ws);
    k0b<<<512, 256, 0, stream>>>(Bmat, ws);
    k0c<<<512, 256, 0, stream>>>(Cmat, ws);
    k1 <<<BL/8, 256, 0, stream>>>(u, ws);
    k2a<<<Bb*NC, 256, 0, stream>>>(ws);
    k2b<<<Bb, 256, 0, stream>>>(ws);
    k2c<<<Bb*NC, 256, 0, stream>>>(ws, out);
    k3 <<<BL/8, 512, 0, stream>>>(u, Dv, ws, out);
}

// Round 4
// 245.803 us; speedup vs baseline: 3.2439x; 3.2439x over previous
//
#include <hip/hip_runtime.h>
#include <hip/hip_bf16.h>

#define Hh 512
#define Pp 256
#define Ll 4096
#define Bb 8
#define BL (Bb*Ll)      // 32768
#define Sc 64
#define NC 64

typedef __attribute__((ext_vector_type(8))) __bf16 bf16x8;
typedef __attribute__((ext_vector_type(4))) float  floatx4;

// ws offsets in float2 units (x8 bytes each; all 16B-aligned)
#define LAM_OFF     0                        // f32 lambda_bar [256]
#define G_OFF       256                      // f32 g [256]
#define LAMS64D_OFF 512                      // double2 lambda^64 [256] (512 slots)
#define B1G_OFF     1024                     // bf16 [512 n][512 k] (65536 slots)
#define B3G_OFF     (B1G_OFF + 65536)        // bf16 [512 n][512 k]
#define UB16_OFF    (B3G_OFF + 65536)        // bf16 u [32768][512] (4194304 slots)
#define XSB_OFF     UB16_OFF                 // reuse: xs bf16 (UB16 dead after k1m)
#define BU_OFF      (UB16_OFF + 4194304)     // float2 Bu [32768][256]
#define AGG_OFF     (BU_OFF + 8388608)
#define CARRY_OFF   (AGG_OFF + 131072)

#define OUT_ELEMS 16777216                   // then state planar [2048 re][2048 im]

#define GLL16(g, l) __builtin_amdgcn_global_load_lds( \
    (const __attribute__((address_space(1))) void*)(g), \
    (__attribute__((address_space(3))) void*)(l), 16, 0, 0)

// ---- K0a: per-p scalars in double ----
__global__ void k0a(const float* __restrict__ Lre, const float* __restrict__ Lim,
                    const float* __restrict__ logstep, float2* __restrict__ ws) {
    int p = threadIdx.x;
    double lr = (double)Lre[p], li = (double)Lim[p];
    double st = exp((double)logstep[p]);
    double a  = lr * st, th = li * st;
    double er = exp(a);
    double lamr = er * cos(th), lami = er * sin(th);
    ws[LAM_OFF + p] = make_float2((float)lamr, (float)lami);
    double er64 = exp(64.0 * a), th64 = 64.0 * th;
    ((double2*)(ws + LAMS64D_OFF))[p] = make_double2(er64 * cos(th64), er64 * sin(th64));
    double nr = lamr - 1.0, ni = lami;
    double den = lr*lr + li*li;
    ws[G_OFF + p] = make_float2((float)((nr*lr + ni*li)/den), (float)((ni*lr - nr*li)/den));
}

// ---- K0b: B1G[n][k]: row 2p = Re(g*B[p][h]), row 2p+1 = Im; bf16 ----
__global__ void k0b(const float* __restrict__ Bmat, float2* __restrict__ ws) {
    int idx = blockIdx.x * 256 + threadIdx.x;   // = p*512+h
    int p = idx >> 9, h = idx & 511;
    float2 b = ((const float2*)Bmat)[idx];
    float2 g = ws[G_OFF + p];
    float re = g.x*b.x - g.y*b.y;
    float im = g.x*b.y + g.y*b.x;
    __hip_bfloat16* B1 = (__hip_bfloat16*)(ws + B1G_OFF);
    B1[(2*p)*512 + h]   = __float2bfloat16(re);
    B1[(2*p+1)*512 + h] = __float2bfloat16(im);
}

// ---- K0c: B3G[n=h][k=2p] = 2*C_re, [2p+1] = -2*C_im; bf16 ----
__global__ void k0c(const float* __restrict__ Cmat, float2* __restrict__ ws) {
    int idx = blockIdx.x * 256 + threadIdx.x;   // = h*256+p
    int h = idx >> 8, p = idx & 255;
    float2 c = ((const float2*)Cmat)[idx];
    __hip_bfloat162* B3 = (__hip_bfloat162*)(ws + B3G_OFF);
    B3[h*256 + p] = __float22bfloat162_rn(make_float2(2.f*c.x, -2.f*c.y));
}

// ---- K0u: u fp32 -> bf16 ----
__global__ void k0u(const float* __restrict__ u, float2* __restrict__ ws) {
    long i = ((long)blockIdx.x * 256 + threadIdx.x) * 4;
    float4 v = *(const float4*)(u + i);
    __hip_bfloat162* ub = (__hip_bfloat162*)(ws + UB16_OFF);
    ub[i/2]     = __float22bfloat162_rn(make_float2(v.x, v.y));
    ub[i/2 + 1] = __float22bfloat162_rn(make_float2(v.z, v.w));
}

// ---- MFMA GEMM: C[M=32768][N=512] = A[M][K=512] * Bg[N][K]^T (bf16 in, fp32 acc)
// m97 structure: 128x128 tile, BK=32, global_load_lds x16, 16x16x32 MFMA.
// EPI=0: Cout = acc (k1 -> Bu). EPI=1: Cout = acc + Dv[col]*u (k3 -> out).
template<int EPI>
__global__ void gemm_mfma(const __hip_bfloat16* __restrict__ Ab,
                          const __hip_bfloat16* __restrict__ Bg,
                          float* __restrict__ Cout,
                          const float* __restrict__ u,
                          const float* __restrict__ Dv) {
    __shared__ __align__(16) char lds[16384];   // A: [0,8K), B: [8K,16K)
    const int tid  = threadIdx.x;
    const int mt   = blockIdx.x >> 2;
    const int nt   = blockIdx.x & 3;
    const long r0  = (long)mt * 128;
    const int  n0  = nt * 128;

    const int seg  = tid & 3;
    const int rowL = tid >> 2;                  // 0..63
    const __hip_bfloat16* Asrc = Ab + (r0 + rowL) * 512 + seg * 8;
    const __hip_bfloat16* Bsrc = Bg + (long)(n0 + rowL) * 512 + seg * 8;
    char* ldsA = lds + tid * 16;
    char* ldsB = lds + 8192 + tid * 16;

    const int lane = tid & 63;
    const int quad = lane >> 4;
    const int ml   = lane & 15;
    const int w    = tid >> 6;
    const int wm   = w & 1, wn = w >> 1;

    floatx4 acc[4][4];
    #pragma unroll
    for (int i = 0; i < 4; ++i)
        #pragma unroll
        for (int j = 0; j < 4; ++j) acc[i][j] = (floatx4)0.f;

    for (int kt = 0; kt < 16; ++kt) {
        __syncthreads();
        GLL16(Asrc + kt*32,             ldsA);
        GLL16(Asrc + kt*32 + 64*512,    ldsA + 4096);
        GLL16(Bsrc + kt*32,             ldsB);
        GLL16(Bsrc + kt*32 + 64*512,    ldsB + 4096);
        __syncthreads();

        bf16x8 af[4], bf[4];
        #pragma unroll
        for (int fm = 0; fm < 4; ++fm)
            af[fm] = *(const bf16x8*)(lds + (wm*64 + fm*16 + ml)*64 + quad*16);
        #pragma unroll
        for (int fn = 0; fn < 4; ++fn)
            bf[fn] = *(const bf16x8*)(lds + 8192 + (wn*64 + fn*16 + ml)*64 + quad*16);
        #pragma unroll
        for (int fm = 0; fm < 4; ++fm)
            #pragma unroll
            for (int fn = 0; fn < 4; ++fn)
                acc[fm][fn] = __builtin_amdgcn_mfma_f32_16x16x32_bf16(af[fm], bf[fn], acc[fm][fn], 0, 0, 0);
    }

    #pragma unroll
    for (int fm = 0; fm < 4; ++fm)
        #pragma unroll
        for (int fn = 0; fn < 4; ++fn) {
            int col = n0 + wn*64 + fn*16 + ml;
            #pragma unroll
            for (int reg = 0; reg < 4; ++reg) {
                long row = r0 + wm*64 + fm*16 + quad*4 + reg;
                long o = row * 512 + col;
                if (EPI == 0) Cout[o] = acc[fm][fn][reg];
                else          Cout[o] = acc[fm][fn][reg] + Dv[col] * u[o];
            }
        }
}

// ---- K2a: per-chunk aggregate ----
__global__ void k2a(float2* __restrict__ ws) {
    int p = threadIdx.x;
    int bc = blockIdx.x;              // b*NC + c
    int b = bc >> 6, c = bc & 63;
    float2 lam = ws[LAM_OFF + p];
    const float2* __restrict__ Bu = ws + BU_OFF + ((long)(b*Ll + c*Sc)) * Pp + p;
    float2 agg = make_float2(0.f, 0.f);
    for (int j = 0; j < Sc; ++j) {
        float2 bu = Bu[(long)j * Pp];
        float nr = fmaf(lam.x, agg.x, bu.x); nr = fmaf(-lam.y, agg.y, nr);
        float ni = fmaf(lam.x, agg.y, bu.y); ni = fmaf( lam.y, agg.x, ni);
        agg.x = nr; agg.y = ni;
    }
    ws[AGG_OFF + bc * Pp + p] = agg;
}

// ---- K2b: chunk-carry chain in double ----
__global__ void k2b(float2* __restrict__ ws) {   // 8 blocks x 256
    int p = threadIdx.x, b = blockIdx.x;
    double2 lS = ((const double2*)(ws + LAMS64D_OFF))[p];
    double cr = 0.0, ci = 0.0;
    for (int c = 0; c < NC; ++c) {
        ws[CARRY_OFF + (b*NC + c) * Pp + p] = make_float2((float)cr, (float)ci);
        float2 a = ws[AGG_OFF + (b*NC + c) * Pp + p];
        double nr = fma(lS.x, cr, (double)a.x); nr = fma(-lS.y, ci, nr);
        double ni = fma(lS.x, ci, (double)a.y); ni = fma( lS.y, cr, ni);
        cr = nr; ci = ni;
    }
}

// ---- K2c: apply carry, write xs as bf16 (interleaved re/im); emit state planar ----
__global__ void k2c(float2* __restrict__ ws, float* __restrict__ dout) {
    int p = threadIdx.x;
    int bc = blockIdx.x;
    int b = bc >> 6, c = bc & 63;
    float2 lam = ws[LAM_OFF + p];
    float2 x = ws[CARRY_OFF + bc * Pp + p];
    const float2* __restrict__ Bu = ws + BU_OFF + ((long)(b*Ll + c*Sc)) * Pp + p;
    __hip_bfloat162* __restrict__ xsb = (__hip_bfloat162*)(ws + XSB_OFF);
    long rbase = (long)(b*Ll + c*Sc) * Pp + p;
    for (int j = 0; j < Sc; ++j) {
        float2 bu = Bu[(long)j * Pp];
        float nr = fmaf(lam.x, x.x, bu.x); nr = fmaf(-lam.y, x.y, nr);
        float ni = fmaf(lam.x, x.y, bu.y); ni = fmaf( lam.y, x.x, ni);
        x.x = nr; x.y = ni;
        xsb[rbase + (long)j * Pp] = __float22bfloat162_rn(make_float2(x.x, x.y));
    }
    if (c == NC - 1) {
        dout[OUT_ELEMS + b * Pp + p] = x.x;
        dout[OUT_ELEMS + Bb * Pp + b * Pp + p] = x.y;
    }
}

extern "C" void kernel_launch(void* const* d_in, const int* in_sizes, int n_in,
                              void* d_out, int out_size, void* d_ws, size_t ws_size,
                              hipStream_t stream) {
    const float* u       = (const float*)d_in[0];
    const float* Lre     = (const float*)d_in[1];
    const float* Lim     = (const float*)d_in[2];
    const float* Bmat    = (const float*)d_in[3];
    const float* Cmat    = (const float*)d_in[4];
    const float* Dv      = (const float*)d_in[5];
    const float* logstep = (const float*)d_in[6];
    float*  out = (float*)d_out;
    float2* ws  = (float2*)d_ws;

    k0a<<<1, 256, 0, stream>>>(Lre, Lim, logstep, ws);
    k0b<<<512, 256, 0, stream>>>(Bmat, ws);
    k0c<<<512, 256, 0, stream>>>(Cmat, ws);
    k0u<<<16384, 256, 0, stream>>>(u, ws);

    gemm_mfma<0><<<1024, 256, 0, stream>>>(
        (const __hip_bfloat16*)(ws + UB16_OFF),
        (const __hip_bfloat16*)(ws + B1G_OFF),
        (float*)(ws + BU_OFF), nullptr, nullptr);

    k2a<<<Bb*NC, 256, 0, stream>>>(ws);
    k2b<<<Bb, 256, 0, stream>>>(ws);
    k2c<<<Bb*NC, 256, 0, stream>>>(ws, out);

    gemm_mfma<1><<<1024, 256, 0, stream>>>(
        (const __hip_bfloat16*)(ws + XSB_OFF),
        (const __hip_bfloat16*)(ws + B3G_OFF),
        out, u, Dv);
}

// Round 5
// 233.777 us; speedup vs baseline: 3.4108x; 1.0514x over previous
//
#include <hip/hip_runtime.h>
#include <hip/hip_bf16.h>

#define Hh 512
#define Pp 256
#define Ll 4096
#define Bb 8
#define BL (Bb*Ll)      // 32768
#define Sc 64
#define NC 64

typedef __attribute__((ext_vector_type(8))) __bf16 bf16x8;
typedef __attribute__((ext_vector_type(4))) float  floatx4;

// ws offsets in float2 units (8 B each; all 16B-aligned)
#define LAM_OFF     0                        // f32 lambda_bar [256]
#define G_OFF       256                      // f32 g [256]
#define LAMS64D_OFF 512                      // double2 lambda^64 [256] (512 slots)
#define B1G_OFF     1024                     // bf16 [512 n][512 k]
#define B3G_OFF     (B1G_OFF + 65536)        // bf16 [512 n][512 k]
#define UB16_OFF    (B3G_OFF + 65536)        // bf16 u [32768][512]
#define XSB_OFF     (UB16_OFF + 4194304)     // bf16 xs [32768][512]
#define BUB_OFF     (XSB_OFF + 4194304)      // bf16 Bu [32768][512]
#define AGG_OFF     (BUB_OFF + 4194304)      // f32 float2 [512*256]

#define OUT_ELEMS 16777216                   // then state planar [2048 re][2048 im]

#define GLL16(g, l) __builtin_amdgcn_global_load_lds( \
    (const __attribute__((address_space(1))) void*)(g), \
    (__attribute__((address_space(3))) void*)(l), 16, 0, 0)

// ---- K0a: per-p scalars in double ----
__global__ void k0a(const float* __restrict__ Lre, const float* __restrict__ Lim,
                    const float* __restrict__ logstep, float2* __restrict__ ws) {
    int p = threadIdx.x;
    double lr = (double)Lre[p], li = (double)Lim[p];
    double st = exp((double)logstep[p]);
    double a  = lr * st, th = li * st;
    double er = exp(a);
    double lamr = er * cos(th), lami = er * sin(th);
    ws[LAM_OFF + p] = make_float2((float)lamr, (float)lami);
    double er64 = exp(64.0 * a), th64 = 64.0 * th;
    ((double2*)(ws + LAMS64D_OFF))[p] = make_double2(er64 * cos(th64), er64 * sin(th64));
    double nr = lamr - 1.0, ni = lami;
    double den = lr*lr + li*li;
    ws[G_OFF + p] = make_float2((float)((nr*lr + ni*li)/den), (float)((ni*lr - nr*li)/den));
}

// ---- K0bc: build both weight matrices (bf16) ----
__global__ void k0bc(const float* __restrict__ Bmat, const float* __restrict__ Cmat,
                     float2* __restrict__ ws) {
    int bid = blockIdx.x;
    if (bid < 512) {
        int idx = bid * 256 + threadIdx.x;      // = p*512+h
        int p = idx >> 9, h = idx & 511;
        float2 b = ((const float2*)Bmat)[idx];
        float2 g = ws[G_OFF + p];
        float re = g.x*b.x - g.y*b.y;
        float im = g.x*b.y + g.y*b.x;
        __hip_bfloat16* B1 = (__hip_bfloat16*)(ws + B1G_OFF);
        B1[(2*p)*512 + h]   = __float2bfloat16(re);
        B1[(2*p+1)*512 + h] = __float2bfloat16(im);
    } else {
        int idx = (bid - 512) * 256 + threadIdx.x;  // = h*256+p
        int h = idx >> 8, p = idx & 255;
        float2 c = ((const float2*)Cmat)[idx];
        __hip_bfloat162* B3 = (__hip_bfloat162*)(ws + B3G_OFF);
        B3[h*256 + p] = __float22bfloat162_rn(make_float2(2.f*c.x, -2.f*c.y));
    }
}

// ---- K0u: u fp32 -> bf16 ----
__global__ void k0u(const float* __restrict__ u, float2* __restrict__ ws) {
    long i = ((long)blockIdx.x * 256 + threadIdx.x) * 4;
    float4 v = *(const float4*)(u + i);
    __hip_bfloat162* ub = (__hip_bfloat162*)(ws + UB16_OFF);
    ub[i/2]     = __float22bfloat162_rn(make_float2(v.x, v.y));
    ub[i/2 + 1] = __float22bfloat162_rn(make_float2(v.z, v.w));
}

// ---- MFMA GEMM: C[32768][512] = A[32768][512] * Bg[512][512]^T, 256x256 tile ----
// EPI=0: write bf16 Bu. EPI=1: write fp32 out = acc + Dv[col]*u_bf16.
template<int EPI>
__global__ __launch_bounds__(512, 2)
void gemm_mfma(const __hip_bfloat16* __restrict__ Ab,
               const __hip_bfloat16* __restrict__ Bg,
               void* __restrict__ Cout,
               const __hip_bfloat16* __restrict__ ub,
               const float* __restrict__ Dv) {
    __shared__ __align__(16) char lds[32768];   // A: [0,16K), B: [16K,32K)
    const int tid = threadIdx.x;
    const int mt  = blockIdx.x >> 1;
    const int nt  = blockIdx.x & 1;
    const long r0 = (long)mt * 256;
    const int  n0 = nt * 256;

    const int rowL = tid >> 2;                  // 0..127
    const int seg  = tid & 3;
    const __hip_bfloat16* Asrc = Ab + (r0 + rowL) * 512 + seg * 8;
    const __hip_bfloat16* Bsrc = Bg + (long)(n0 + rowL) * 512 + seg * 8;
    char* ldsA = lds + tid * 16;
    char* ldsB = lds + 16384 + tid * 16;

    const int lane = tid & 63;
    const int quad = lane >> 4;
    const int ml   = lane & 15;
    const int w    = tid >> 6;                  // 0..7
    const int wm   = w & 3;                     // row group: wm*64
    const int wn   = w >> 2;                    // col group: wn*128

    floatx4 acc[4][8];
    #pragma unroll
    for (int i = 0; i < 4; ++i)
        #pragma unroll
        for (int j = 0; j < 8; ++j) acc[i][j] = (floatx4)0.f;

    for (int kt = 0; kt < 16; ++kt) {
        __syncthreads();
        GLL16(Asrc + kt*32,             ldsA);
        GLL16(Asrc + kt*32 + 128*512,   ldsA + 8192);
        GLL16(Bsrc + kt*32,             ldsB);
        GLL16(Bsrc + kt*32 + 128*512,   ldsB + 8192);
        __syncthreads();

        bf16x8 af[4], bf[8];
        #pragma unroll
        for (int fm = 0; fm < 4; ++fm)
            af[fm] = *(const bf16x8*)(lds + (wm*64 + fm*16 + ml)*64 + quad*16);
        #pragma unroll
        for (int fn = 0; fn < 8; ++fn)
            bf[fn] = *(const bf16x8*)(lds + 16384 + (wn*128 + fn*16 + ml)*64 + quad*16);
        #pragma unroll
        for (int fm = 0; fm < 4; ++fm)
            #pragma unroll
            for (int fn = 0; fn < 8; ++fn)
                acc[fm][fn] = __builtin_amdgcn_mfma_f32_16x16x32_bf16(af[fm], bf[fn], acc[fm][fn], 0, 0, 0);
    }

    #pragma unroll
    for (int fm = 0; fm < 4; ++fm)
        #pragma unroll
        for (int fn = 0; fn < 8; ++fn) {
            int col = n0 + wn*128 + fn*16 + ml;
            #pragma unroll
            for (int reg = 0; reg < 4; ++reg) {
                long row = r0 + wm*64 + fm*16 + quad*4 + reg;
                long o = row * 512 + col;
                if (EPI == 0) {
                    ((__hip_bfloat16*)Cout)[o] = __float2bfloat16(acc[fm][fn][reg]);
                } else {
                    ((float*)Cout)[o] = acc[fm][fn][reg] + Dv[col] * __bfloat162float(ub[o]);
                }
            }
        }
}

// ---- K2a: per-chunk aggregate from bf16 Bu ----
__global__ void k2a(float2* __restrict__ ws) {
    int p = threadIdx.x;
    int bc = blockIdx.x;              // b*NC + c
    int b = bc >> 6, c = bc & 63;
    float2 lam = ws[LAM_OFF + p];
    const __hip_bfloat162* __restrict__ bub = (const __hip_bfloat162*)(ws + BUB_OFF);
    long base = (long)(b*Ll + c*Sc) * Pp + p;
    float2 agg = make_float2(0.f, 0.f);
    for (int j = 0; j < Sc; ++j) {
        float2 bu = __bfloat1622float2(bub[base + (long)j * Pp]);
        float nr = fmaf(lam.x, agg.x, bu.x); nr = fmaf(-lam.y, agg.y, nr);
        float ni = fmaf(lam.x, agg.y, bu.y); ni = fmaf( lam.y, agg.x, ni);
        agg.x = nr; agg.y = ni;
    }
    ws[AGG_OFF + bc * Pp + p] = agg;
}

// ---- K2c: per-block fp64 carry chain, then apply + write xs bf16 + state ----
__global__ void k2c(float2* __restrict__ ws, float* __restrict__ dout) {
    int p = threadIdx.x;
    int bc = blockIdx.x;
    int b = bc >> 6, c = bc & 63;
    float2 lam = ws[LAM_OFF + p];
    double2 l64 = ((const double2*)(ws + LAMS64D_OFF))[p];
    double cr = 0.0, ci = 0.0;
    for (int cp = 0; cp < c; ++cp) {
        float2 a = ws[AGG_OFF + (b*NC + cp) * Pp + p];
        double nr = fma(l64.x, cr, (double)a.x); nr = fma(-l64.y, ci, nr);
        double ni = fma(l64.x, ci, (double)a.y); ni = fma( l64.y, cr, ni);
        cr = nr; ci = ni;
    }
    float2 x = make_float2((float)cr, (float)ci);
    const __hip_bfloat162* __restrict__ bub = (const __hip_bfloat162*)(ws + BUB_OFF);
    __hip_bfloat162* __restrict__ xsb = (__hip_bfloat162*)(ws + XSB_OFF);
    long base = (long)(b*Ll + c*Sc) * Pp + p;
    for (int j = 0; j < Sc; ++j) {
        float2 bu = __bfloat1622float2(bub[base + (long)j * Pp]);
        float nr = fmaf(lam.x, x.x, bu.x); nr = fmaf(-lam.y, x.y, nr);
        float ni = fmaf(lam.x, x.y, bu.y); ni = fmaf( lam.y, x.x, ni);
        x.x = nr; x.y = ni;
        xsb[base + (long)j * Pp] = __float22bfloat162_rn(make_float2(x.x, x.y));
    }
    if (c == NC - 1) {
        dout[OUT_ELEMS + b * Pp + p] = x.x;
        dout[OUT_ELEMS + Bb * Pp + b * Pp + p] = x.y;
    }
}

extern "C" void kernel_launch(void* const* d_in, const int* in_sizes, int n_in,
                              void* d_out, int out_size, void* d_ws, size_t ws_size,
                              hipStream_t stream) {
    const float* u       = (const float*)d_in[0];
    const float* Lre     = (const float*)d_in[1];
    const float* Lim     = (const float*)d_in[2];
    const float* Bmat    = (const float*)d_in[3];
    const float* Cmat    = (const float*)d_in[4];
    const float* Dv      = (const float*)d_in[5];
    const float* logstep = (const float*)d_in[6];
    float*  out = (float*)d_out;
    float2* ws  = (float2*)d_ws;

    k0a<<<1, 256, 0, stream>>>(Lre, Lim, logstep, ws);
    k0bc<<<1024, 256, 0, stream>>>(Bmat, Cmat, ws);
    k0u<<<16384, 256, 0, stream>>>(u, ws);

    gemm_mfma<0><<<256, 512, 0, stream>>>(
        (const __hip_bfloat16*)(ws + UB16_OFF),
        (const __hip_bfloat16*)(ws + B1G_OFF),
        (void*)(ws + BUB_OFF), nullptr, nullptr);

    k2a<<<Bb*NC, 256, 0, stream>>>(ws);
    k2c<<<Bb*NC, 256, 0, stream>>>(ws, out);

    gemm_mfma<1><<<256, 512, 0, stream>>>(
        (const __hip_bfloat16*)(ws + XSB_OFF),
        (const __hip_bfloat16*)(ws + B3G_OFF),
        (void*)out,
        (const __hip_bfloat16*)(ws + UB16_OFF), Dv);
}